// Round 17
// baseline (453.258 us; speedup 1.0000x reference)
//
#include <hip/hip_runtime.h>

#define DM 128
#define NH 8
#define DH 16

typedef __bf16 bf8 __attribute__((ext_vector_type(8)));
typedef __bf16 bf4 __attribute__((ext_vector_type(4)));
typedef float  f4  __attribute__((ext_vector_type(4)));

__device__ __forceinline__ f4 mfma16(bf8 a, bf8 b, f4 c){
  return __builtin_amdgcn_mfma_f32_16x16x32_bf16(a, b, c, 0, 0, 0);
}

__device__ __forceinline__ bf8 bfragT(const __bf16* __restrict__ WT, int ldk, int lane){
  const __bf16* p = WT + (size_t)(lane & 15) * ldk + ((lane >> 4) << 3);
  return *(const bf8*)p;
}

__device__ __forceinline__ bf8 cvt8(const float* __restrict__ p){
  f4 u = *(const f4*)p;
  f4 v = *(const f4*)(p + 4);
  bf8 r;
  r[0]=(__bf16)u[0]; r[1]=(__bf16)u[1]; r[2]=(__bf16)u[2]; r[3]=(__bf16)u[3];
  r[4]=(__bf16)v[0]; r[5]=(__bf16)v[1]; r[6]=(__bf16)v[2]; r[7]=(__bf16)v[3];
  return r;
}

// ---------------- weight transposes + dst histogram in ONE launch ----------------
__global__ __launch_bounds__(256) void k_prep_hist(const float* __restrict__ Wq,
    const float* __restrict__ Wk, const float* __restrict__ Wv,
    const float* __restrict__ We, const float* __restrict__ Wo,
    const float* __restrict__ W1, const float* __restrict__ W2,
    __bf16* __restrict__ WqT, __bf16* __restrict__ WkT, __bf16* __restrict__ WvT,
    __bf16* __restrict__ WeT, __bf16* __restrict__ WoT,
    __bf16* __restrict__ W1T, __bf16* __restrict__ W2T,
    const int* __restrict__ dst, int* __restrict__ deg, int E)
{
  int b = blockIdx.x;
  if (b >= 576){
    int i = (b - 576) * 256 + threadIdx.x;
    if (i < E) atomicAdd(&deg[dst[i]], 1);
    return;
  }
  const float* W; __bf16* T; int K, M, idx;
  if (b < 320){
    int w = b >> 6;
    W = w==0?Wq: w==1?Wk: w==2?Wv: w==3?We: Wo;
    T = w==0?WqT: w==1?WkT: w==2?WvT: w==3?WeT: WoT;
    K = 128; M = 128; idx = (b & 63) * 256 + threadIdx.x;
  } else if (b < 448){
    W = W1; T = W1T; K = 128; M = 256; idx = (b - 320) * 256 + threadIdx.x;
  } else {
    W = W2; T = W2T; K = 256; M = 128; idx = (b - 448) * 256 + threadIdx.x;
  }
  int m = idx / K, k = idx - m * K;
  T[idx] = (__bf16)W[(size_t)k * M + m];
}

// ---------------- parallel 3-phase exclusive scan of deg -> off, cursor ----------------
__global__ __launch_bounds__(256) void k_scanA(const int* __restrict__ deg,
    int* __restrict__ part, int N)
{
  __shared__ int ls[256];
  int b = blockIdx.x, t = threadIdx.x;
  int i = b * 256 + t;
  ls[t] = (i < N) ? deg[i] : 0;
  __syncthreads();
  for (int d = 128; d > 0; d >>= 1){
    if (t < d) ls[t] += ls[t + d];
    __syncthreads();
  }
  if (t == 0) part[b] = ls[0];
}

__global__ __launch_bounds__(256) void k_scanB(int* __restrict__ part, int nb)
{
  __shared__ int ls[256];
  int t = threadIdx.x;
  ls[t] = (t < nb) ? part[t] : 0;
  __syncthreads();
  for (int d = 1; d < 256; d <<= 1){
    int add = (t >= d) ? ls[t - d] : 0;
    __syncthreads();
    ls[t] += add;
    __syncthreads();
  }
  if (t < nb) part[t] = (t == 0) ? 0 : ls[t - 1];   // exclusive block offsets
}

__global__ __launch_bounds__(256) void k_scanC(const int* __restrict__ deg,
    const int* __restrict__ part, int* __restrict__ off, int* __restrict__ cursor, int N)
{
  __shared__ int ls[256];
  int b = blockIdx.x, t = threadIdx.x;
  int i = b * 256 + t;
  int v = (i < N) ? deg[i] : 0;
  ls[t] = v;
  __syncthreads();
  for (int d = 1; d < 256; d <<= 1){
    int add = (t >= d) ? ls[t - d] : 0;
    __syncthreads();
    ls[t] += add;
    __syncthreads();
  }
  if (i < N){
    int excl = ls[t] - v + part[b];
    off[i] = excl;
    cursor[i] = excl;
  }
}

// ---------------- K1: Q,K,V = h @ Wq/Wk/Wv  (bf16 outputs) ----------------
__global__ __launch_bounds__(256) void k_qkv(const float* __restrict__ h,
    const __bf16* __restrict__ WqT, const __bf16* __restrict__ WkT, const __bf16* __restrict__ WvT,
    __bf16* __restrict__ Q, __bf16* __restrict__ K, __bf16* __restrict__ V, int N)
{
  int lane = threadIdx.x & 63;
  int r0 = (blockIdx.x * 4 + (threadIdx.x >> 6)) * 16;
  if (r0 + 16 > N) return;
  bf8 a[4];
  int arow = r0 + (lane & 15);
  int koff = (lane >> 4) << 3;
#pragma unroll
  for (int kt = 0; kt < 4; ++kt)
    a[kt] = cvt8(h + (size_t)arow * DM + kt * 32 + koff);

  const __bf16* Ws[3] = {WqT, WkT, WvT};
  __bf16* Os[3] = {Q, K, V};
  int crow = r0 + ((lane >> 4) << 2);
  int ccol = lane & 15;
#pragma unroll
  for (int o = 0; o < 3; ++o){
#pragma unroll
    for (int nt = 0; nt < 8; ++nt){
      f4 acc = {0.f, 0.f, 0.f, 0.f};
#pragma unroll
      for (int kt = 0; kt < 4; ++kt)
        acc = mfma16(a[kt], bfragT(Ws[o] + (size_t)(nt * 16) * DM + kt * 32, DM, lane), acc);
      __bf16* outp = Os[o] + (size_t)crow * DM + nt * 16 + ccol;
      outp[0] = (__bf16)acc[0]; outp[DM] = (__bf16)acc[1];
      outp[2 * DM] = (__bf16)acc[2]; outp[3 * DM] = (__bf16)acc[3];
    }
  }
}

// ---------------- K2: persistent pipelined Eh GEMM + edge scoring (frozen since R12) ----------------
__global__ __launch_bounds__(256) void k_edge(const float* __restrict__ e,
    const __bf16* __restrict__ WeT,
    const __bf16* __restrict__ Qb, const __bf16* __restrict__ Kb,
    const int* __restrict__ src, const int* __restrict__ dst,
    int* __restrict__ cursor, int* __restrict__ sSrc, float* __restrict__ sS,
    int E, int T, int NW)
{
  __shared__ __bf16 Eh[64][132];
  int tid = threadIdx.x, lane = tid & 63, wave = tid >> 6;
  int l16 = lane & 15;
  int koff = (lane >> 4) << 3;
  int half = lane >> 5, l32 = lane & 31, hh = l32 >> 2;
  int lrow = (lane >> 4) << 2;
  int wrow = wave * 16;
  int t = blockIdx.x * 4 + wave;
  if (t >= T) return;

  // ---- prologue: stage tile t ----
  int ei = min(t * 16 + l16, E - 1);
  int sv = src[ei], dv = dst[ei];
  int slotv = 0;
  if ((lane < 16) && (t * 16 + l16 < E)){
    slotv = atomicAdd(&cursor[dv], 1);
    sSrc[slotv] = sv;
  }
  f4 eu[4], ew[4];
#pragma unroll
  for (int kt = 0; kt < 4; ++kt){
    const float* p = e + (size_t)ei * DM + kt * 32 + koff;
    eu[kt] = *(const f4*)p; ew[kt] = *(const f4*)(p + 4);
  }
  bf4 kr[8], qr[8];
#pragma unroll
  for (int i = 0; i < 8; ++i){
    int js = __shfl(sv, i * 2 + half, 64);
    int jd = __shfl(dv, i * 2 + half, 64);
    kr[i] = *(const bf4*)(Kb + (size_t)js * DM + l32 * 4);
    qr[i] = *(const bf4*)(Qb + (size_t)jd * DM + l32 * 4);
  }

  while (t < T){
    int tn = t + NW;
    bool hn = (tn < T);
    // A fragments
    bf8 a[4];
#pragma unroll
    for (int kt = 0; kt < 4; ++kt){
      bf8 r;
      r[0]=(__bf16)eu[kt][0]; r[1]=(__bf16)eu[kt][1]; r[2]=(__bf16)eu[kt][2]; r[3]=(__bf16)eu[kt][3];
      r[4]=(__bf16)ew[kt][0]; r[5]=(__bf16)ew[kt][1]; r[6]=(__bf16)ew[kt][2]; r[7]=(__bf16)ew[kt][3];
      a[kt] = r;
    }
    // next-tile meta loads (early issue)
    int svn = 0, dvn = 0, slotn = 0;
    if (hn){
      int ein = min(tn * 16 + l16, E - 1);
      svn = src[ein]; dvn = dst[ein];
    }
    // MFMA tile t -> wave-private Eh rows
#pragma unroll
    for (int nt = 0; nt < 8; ++nt){
      f4 acc = {0.f, 0.f, 0.f, 0.f};
#pragma unroll
      for (int kt = 0; kt < 4; ++kt)
        acc = mfma16(a[kt], bfragT(WeT + (size_t)(nt * 16) * DM + kt * 32, DM, lane), acc);
      int col = nt * 16 + l16;
#pragma unroll
      for (int r = 0; r < 4; ++r) Eh[wrow + lrow + r][col] = (__bf16)acc[r];
    }
    // stage next e-rows + next slot (latency hides under consume below)
    if (hn){
      int ern = min(tn * 16 + l16, E - 1);
#pragma unroll
      for (int kt = 0; kt < 4; ++kt){
        const float* p = e + (size_t)ern * DM + kt * 32 + koff;
        eu[kt] = *(const f4*)p; ew[kt] = *(const f4*)(p + 4);
      }
      if ((lane < 16) && (tn * 16 + l16 < E)){
        slotn = atomicAdd(&cursor[dvn], 1);
        sSrc[slotn] = svn;
      }
    }
    // consume part 1: dot products + reduce (frees kr/qr)
    float ds[8];
#pragma unroll
    for (int q = 0; q < 8; ++q){
      bf4 evv = *(const bf4*)&Eh[wrow + q * 2 + half][l32 * 4];
      bf4 kv = kr[q], qv = qr[q];
      float d = (float)kv[0]*(float)qv[0]*(float)evv[0]
              + (float)kv[1]*(float)qv[1]*(float)evv[1]
              + (float)kv[2]*(float)qv[2]*(float)evv[2]
              + (float)kv[3]*(float)qv[3]*(float)evv[3];
      d += __shfl_xor(d, 1);
      d += __shfl_xor(d, 2);
      ds[q] = d;
    }
    // issue next-tile gathers now that kr/qr are dead (cover expf + next MFMA)
    if (hn){
#pragma unroll
      for (int i = 0; i < 8; ++i){
        int js = __shfl(svn, i * 2 + half, 64);
        int jd = __shfl(dvn, i * 2 + half, 64);
        kr[i] = *(const bf4*)(Kb + (size_t)js * DM + l32 * 4);
        qr[i] = *(const bf4*)(Qb + (size_t)jd * DM + l32 * 4);
      }
    }
    // consume part 2: broadcast slots wave-uniformly (width 64!), then clamp/exp/store
    int jslot[8];
#pragma unroll
    for (int q = 0; q < 8; ++q) jslot[q] = __shfl(slotv, q * 2 + half, 64);
    if ((l32 & 3) == 0){
#pragma unroll
      for (int q = 0; q < 8; ++q){
        if ((t * 16 + q * 2 + half) < E){
          float dd = fminf(5.f, fmaxf(-5.f, ds[q] * 0.25f));
          sS[(size_t)jslot[q] * NH + hh] = __expf(dd);
        }
      }
    }
    sv = svn; dv = dvn; slotv = slotn;
    t = tn;
  }
}

// ---------------- K2c: per-node gather (split for TLP: 8 nodes/block -> 6250 blocks) ----------------
__global__ __launch_bounds__(256) void k_gather(const int* __restrict__ off,
    const int* __restrict__ cend, const int* __restrict__ sSrc, const float* __restrict__ sS,
    const __bf16* __restrict__ Vb, __bf16* __restrict__ hattn, int N)
{
  int lane = threadIdx.x & 63;
  int half = lane >> 5, l32 = lane & 31;
  int node = blockIdx.x * 8 + (threadIdx.x >> 6) * 2 + half;
  if (node >= N) return;
  int start = off[node], end = cend[node];
  int hh = l32 >> 2;
  float a0 = 0.f, a1 = 0.f, a2 = 0.f, a3 = 0.f, z = 0.f;
  for (int base = start; base < end; base += 8){
    int idx[8], sj[8]; float s[8];
#pragma unroll
    for (int q = 0; q < 8; ++q) idx[q] = min(base + q, end - 1);
#pragma unroll
    for (int q = 0; q < 8; ++q) sj[q] = sSrc[idx[q]];
#pragma unroll
    for (int q = 0; q < 8; ++q) s[q] = (base + q < end) ? sS[(size_t)idx[q] * NH + hh] : 0.f;
#pragma unroll
    for (int q = 0; q < 8; ++q){
      bf4 v = *(const bf4*)(Vb + (size_t)sj[q] * DM + l32 * 4);
      a0 += s[q] * (float)v[0]; a1 += s[q] * (float)v[1];
      a2 += s[q] * (float)v[2]; a3 += s[q] * (float)v[3];
      z += s[q];
    }
  }
  float invz = 1.f / (z + 1e-6f);
  bf4 o;
  o[0] = (__bf16)(a0 * invz); o[1] = (__bf16)(a1 * invz);
  o[2] = (__bf16)(a2 * invz); o[3] = (__bf16)(a3 * invz);
  *(bf4*)(hattn + (size_t)node * DM + l32 * 4) = o;
}

// ---------------- K3: h2 = h + h_attn @ Wo + bo  (bf16 out) + fused BN1 stats ----------------
__global__ __launch_bounds__(256) void k_attnout(const __bf16* __restrict__ hattn,
    const float* __restrict__ h,
    const __bf16* __restrict__ WoT, const float* __restrict__ bo,
    __bf16* __restrict__ h2, float* __restrict__ s1, float* __restrict__ s2, int N)
{
  __shared__ float ls[256];
  int tid = threadIdx.x;
  ls[tid] = 0.f;
  __syncthreads();
  int lane = tid & 63;
  int r0 = (blockIdx.x * 4 + (tid >> 6)) * 16;
  bool active = (r0 + 16 <= N);
  int r0c = active ? r0 : 0;
  int arow = r0c + (lane & 15);
  int kof = (lane >> 4) << 3;
  bf8 a[4];
#pragma unroll
  for (int kt = 0; kt < 4; ++kt)
    a[kt] = *(const bf8*)(hattn + (size_t)arow * DM + kt * 32 + kof);
  int crow = r0c + ((lane >> 4) << 2);
  int ccol = lane & 15;
#pragma unroll
  for (int nt = 0; nt < 8; ++nt){
    f4 acc = {0.f, 0.f, 0.f, 0.f};
#pragma unroll
    for (int kt = 0; kt < 4; ++kt)
      acc = mfma16(a[kt], bfragT(WoT + (size_t)(nt * 16) * DM + kt * 32, DM, lane), acc);
    int col = nt * 16 + ccol;
    float bb = bo[col];
    if (active){
      float p1 = 0.f, p2 = 0.f;
#pragma unroll
      for (int r = 0; r < 4; ++r){
        size_t idx = (size_t)(crow + r) * DM + col;
        float v = h[idx] + acc[r] + bb;
        h2[idx] = (__bf16)v;
        p1 += v; p2 += v * v;
      }
      atomicAdd(&ls[col], p1);
      atomicAdd(&ls[128 + col], p2);
    }
  }
  __syncthreads();
  if (tid < 128){
    atomicAdd(&s1[tid], ls[tid]);
    atomicAdd(&s2[tid], ls[128 + tid]);
  }
}

// ---------------- K6: FFN fused, BN1 coefs per-block, bf16 output + BN2 stats ----------------
__global__ __launch_bounds__(256) void k_ffn(const __bf16* __restrict__ h2,
    const float* __restrict__ s1a, const float* __restrict__ s2a,
    const float* __restrict__ g1, const float* __restrict__ be1,
    const __bf16* __restrict__ W1T, const float* __restrict__ b1,
    const __bf16* __restrict__ W2T, const float* __restrict__ b2,
    __bf16* __restrict__ y, float* __restrict__ s1, float* __restrict__ s2, int N)
{
  __shared__ __bf16 hid[4][16][264];   // padded: breaks 16-way bank conflict on GEMM2 reads
  __shared__ float ls[256];
  __shared__ float cls[128], clb[128];
  int tid = threadIdx.x;
  ls[tid] = 0.f;
  if (tid < 128){
    float mean = s1a[tid] / (float)N;
    float var  = s2a[tid] / (float)N - mean * mean;
    float rs   = rsqrtf(var + 1e-5f);
    float sc   = g1[tid] * rs;
    cls[tid] = sc;
    clb[tid] = be1[tid] - mean * sc;
  }
  __syncthreads();
  int lane = tid & 63, wave = tid >> 6;
  int r0 = (blockIdx.x * 4 + wave) * 16;
  bool active = (r0 + 16 <= N);
  int r0c = active ? r0 : 0;

  int arow = r0c + (lane & 15);
  int kof = (lane >> 4) << 3;
  bf8 a[4];
#pragma unroll
  for (int kt = 0; kt < 4; ++kt){
    int kb = kt * 32 + kof;
    bf8 hv = *(const bf8*)(h2 + (size_t)arow * DM + kb);
    bf8 r;
#pragma unroll
    for (int j = 0; j < 8; ++j)
      r[j] = (__bf16)((float)hv[j] * cls[kb + j] + clb[kb + j]);
    a[kt] = r;
  }
  int lr = (lane >> 4) << 2;
  int ccol = lane & 15;
#pragma unroll
  for (int nt = 0; nt < 16; ++nt){
    f4 acc = {0.f, 0.f, 0.f, 0.f};
#pragma unroll
    for (int kt = 0; kt < 4; ++kt)
      acc = mfma16(a[kt], bfragT(W1T + (size_t)(nt * 16) * DM + kt * 32, DM, lane), acc);
    int col = nt * 16 + ccol;
    float bb = b1[col];
#pragma unroll
    for (int r = 0; r < 4; ++r)
      hid[wave][lr + r][col] = (__bf16)fmaxf(acc[r] + bb, 0.f);
  }
  __syncthreads();
  f4 acc2[8];
#pragma unroll
  for (int nt = 0; nt < 8; ++nt){ acc2[nt][0]=0.f; acc2[nt][1]=0.f; acc2[nt][2]=0.f; acc2[nt][3]=0.f; }
#pragma unroll
  for (int kt = 0; kt < 8; ++kt){
    bf8 a2 = *(const bf8*)&hid[wave][lane & 15][kt * 32 + kof];
#pragma unroll
    for (int nt = 0; nt < 8; ++nt)
      acc2[nt] = mfma16(a2, bfragT(W2T + (size_t)(nt * 16) * 256 + kt * 32, 256, lane), acc2[nt]);
  }
  int crow = r0c + lr;
#pragma unroll
  for (int nt = 0; nt < 8; ++nt){
    int col = nt * 16 + ccol;
    float bb = b2[col], sc = cls[col], sb = clb[col];
    if (active){
      float p1 = 0.f, p2 = 0.f;
#pragma unroll
      for (int r = 0; r < 4; ++r){
        size_t idx = (size_t)(crow + r) * DM + col;
        float xres = (float)h2[idx] * sc + sb;
        float v = acc2[nt][r] + bb + xres;
        __bf16 vb = (__bf16)v;
        y[idx] = vb;
        float vr = (float)vb;        // stats on rounded value => BN exact over y
        p1 += vr; p2 += vr * vr;
      }
      atomicAdd(&ls[col], p1);
      atomicAdd(&ls[128 + col], p2);
    }
  }
  __syncthreads();
  if (tid < 128){
    atomicAdd(&s1[tid], ls[tid]);
    atomicAdd(&s2[tid], ls[128 + tid]);
  }
}

// ---------------- BN2 apply: bf16 in -> f32 out, per-block coef recompute ----------------
__global__ __launch_bounds__(256) void k_bnapply(const __bf16* __restrict__ y,
    float* __restrict__ out,
    const float* __restrict__ s1, const float* __restrict__ s2,
    const float* __restrict__ gam, const float* __restrict__ bet,
    int N, long long total4)
{
  __shared__ float cs[128], cb[128];
  int tid = threadIdx.x;
  if (tid < 128){
    float mean = s1[tid] / (float)N;
    float var  = s2[tid] / (float)N - mean * mean;
    float rs   = rsqrtf(var + 1e-5f);
    float sc   = gam[tid] * rs;
    cs[tid] = sc;
    cb[tid] = bet[tid] - mean * sc;
  }
  __syncthreads();
  long long i = (long long)blockIdx.x * blockDim.x + tid;
  if (i >= total4) return;
  bf4 v = *((const bf4*)y + i);
  int c = (int)((i * 4) & (DM - 1));
  f4 o;
  o[0] = (float)v[0] * cs[c]     + cb[c];
  o[1] = (float)v[1] * cs[c + 1] + cb[c + 1];
  o[2] = (float)v[2] * cs[c + 2] + cb[c + 2];
  o[3] = (float)v[3] * cs[c + 3] + cb[c + 3];
  *((f4*)out + i) = o;
}

// ---------------- host ----------------
extern "C" void kernel_launch(void* const* d_in, const int* in_sizes, int n_in,
                              void* d_out, int out_size, void* d_ws, size_t ws_size,
                              hipStream_t stream)
{
  const float* h    = (const float*)d_in[0];
  const float* e    = (const float*)d_in[2];
  const float* Wq   = (const float*)d_in[3];
  const float* Wk   = (const float*)d_in[4];
  const float* We   = (const float*)d_in[5];
  const float* Wv   = (const float*)d_in[6];
  const float* Wo   = (const float*)d_in[7];
  const float* bo   = (const float*)d_in[8];
  const float* bn1g = (const float*)d_in[9];
  const float* bn1b = (const float*)d_in[10];
  const float* bn2g = (const float*)d_in[11];
  const float* bn2b = (const float*)d_in[12];
  const float* W1   = (const float*)d_in[13];
  const float* b1   = (const float*)d_in[14];
  const float* W2   = (const float*)d_in[15];
  const float* b2   = (const float*)d_in[16];
  const int*   src  = (const int*)d_in[17];
  const int*   dst  = (const int*)d_in[18];

  int N = in_sizes[0] / DM;
  int E = in_sizes[2] / DM;
  float* out = (float*)d_out;

  char* ws = (char*)d_ws;
  size_t off_b = 0;
  auto alloc = [&](size_t bytes) -> char* {
    char* r = ws + off_b;
    off_b += (bytes + 255) & ~(size_t)255;
    return r;
  };
  __bf16* Qb    = (__bf16*)alloc((size_t)N * DM * 2);
  __bf16* Kb    = (__bf16*)alloc((size_t)N * DM * 2);
  __bf16* Vb    = (__bf16*)alloc((size_t)N * DM * 2);
  __bf16* hattn = (__bf16*)alloc((size_t)N * DM * 2);
  __bf16* h2    = (__bf16*)alloc((size_t)N * DM * 2);
  __bf16* y     = (__bf16*)alloc((size_t)N * DM * 2);
  int*   deg    = (int*)alloc((size_t)N * 4);
  int*   offs   = (int*)alloc((size_t)N * 4);
  int*   cursor = (int*)alloc((size_t)N * 4);
  int*   part   = (int*)alloc(256 * 4);
  int*   sSrc   = (int*)alloc((size_t)E * 4);
  float* sS     = (float*)alloc((size_t)E * NH * 4);
  float* stats = (float*)alloc(512 * 4);   // s1a s2a s1b s2b
  float* s1a = stats, *s2a = stats + 128, *s1b = stats + 256, *s2b = stats + 384;
  __bf16* WqT = (__bf16*)alloc(16384 * 2);
  __bf16* WkT = (__bf16*)alloc(16384 * 2);
  __bf16* WvT = (__bf16*)alloc(16384 * 2);
  __bf16* WeT = (__bf16*)alloc(16384 * 2);
  __bf16* WoT = (__bf16*)alloc(16384 * 2);
  __bf16* W1T = (__bf16*)alloc(32768 * 2);
  __bf16* W2T = (__bf16*)alloc(32768 * 2);

  hipMemsetAsync(deg, 0, (size_t)N * 4, stream);
  hipMemsetAsync(stats, 0, 512 * 4, stream);

  int histblocks = (E + 255) / 256;
  k_prep_hist<<<576 + histblocks, 256, 0, stream>>>(Wq, Wk, Wv, We, Wo, W1, W2,
      WqT, WkT, WvT, WeT, WoT, W1T, W2T, dst, deg, E);
  int scb = (N + 255) / 256;    // 196 for N=50000 (fits k_scanB's 256-thread scan)
  k_scanA<<<scb, 256, 0, stream>>>(deg, part, N);
  k_scanB<<<1, 256, 0, stream>>>(part, scb);
  k_scanC<<<scb, 256, 0, stream>>>(deg, part, offs, cursor, N);

  int rowblocks = (N / 16 + 3) / 4;
  k_qkv<<<rowblocks, 256, 0, stream>>>(h, WqT, WkT, WvT, Qb, Kb, Vb, N);
  int T = (E + 15) / 16;
  int eblocks = 2048;
  int NW = eblocks * 4;
  k_edge<<<eblocks, 256, 0, stream>>>(e, WeT, Qb, Kb, src, dst, cursor, sSrc, sS, E, T, NW);
  k_gather<<<(N + 7) / 8, 256, 0, stream>>>(offs, cursor, sSrc, sS, Vb, hattn, N);
  k_attnout<<<rowblocks, 256, 0, stream>>>(hattn, h, WoT, bo, h2, s1a, s2a, N);
  k_ffn<<<rowblocks, 256, 0, stream>>>(h2, s1a, s2a, bn1g, bn1b, W1T, b1, W2T, b2,
                                       y, s1b, s2b, N);
  long long total4 = (long long)N * DM / 4;
  k_bnapply<<<(int)((total4 + 255) / 256), 256, 0, stream>>>(y, out, s1b, s2b, bn2g, bn2b, N, total4);
}

// Round 18
// 446.741 us; speedup vs baseline: 1.0146x; 1.0146x over previous
//
#include <hip/hip_runtime.h>

#define DM 128
#define NH 8
#define DH 16

typedef __bf16 bf8 __attribute__((ext_vector_type(8)));
typedef __bf16 bf4 __attribute__((ext_vector_type(4)));
typedef float  f4  __attribute__((ext_vector_type(4)));

__device__ __forceinline__ f4 mfma16(bf8 a, bf8 b, f4 c){
  return __builtin_amdgcn_mfma_f32_16x16x32_bf16(a, b, c, 0, 0, 0);
}

__device__ __forceinline__ bf8 bfragT(const __bf16* __restrict__ WT, int ldk, int lane){
  const __bf16* p = WT + (size_t)(lane & 15) * ldk + ((lane >> 4) << 3);
  return *(const bf8*)p;
}

__device__ __forceinline__ bf8 cvt8(const float* __restrict__ p){
  f4 u = *(const f4*)p;
  f4 v = *(const f4*)(p + 4);
  bf8 r;
  r[0]=(__bf16)u[0]; r[1]=(__bf16)u[1]; r[2]=(__bf16)u[2]; r[3]=(__bf16)u[3];
  r[4]=(__bf16)v[0]; r[5]=(__bf16)v[1]; r[6]=(__bf16)v[2]; r[7]=(__bf16)v[3];
  return r;
}

// ---------------- weight transposes + dst histogram in ONE launch ----------------
__global__ __launch_bounds__(256) void k_prep_hist(const float* __restrict__ Wq,
    const float* __restrict__ Wk, const float* __restrict__ Wv,
    const float* __restrict__ We, const float* __restrict__ Wo,
    const float* __restrict__ W1, const float* __restrict__ W2,
    __bf16* __restrict__ WqT, __bf16* __restrict__ WkT, __bf16* __restrict__ WvT,
    __bf16* __restrict__ WeT, __bf16* __restrict__ WoT,
    __bf16* __restrict__ W1T, __bf16* __restrict__ W2T,
    const int* __restrict__ dst, int* __restrict__ deg, int E)
{
  int b = blockIdx.x;
  if (b >= 576){
    int i = (b - 576) * 256 + threadIdx.x;
    if (i < E) atomicAdd(&deg[dst[i]], 1);
    return;
  }
  const float* W; __bf16* T; int K, M, idx;
  if (b < 320){
    int w = b >> 6;
    W = w==0?Wq: w==1?Wk: w==2?Wv: w==3?We: Wo;
    T = w==0?WqT: w==1?WkT: w==2?WvT: w==3?WeT: WoT;
    K = 128; M = 128; idx = (b & 63) * 256 + threadIdx.x;
  } else if (b < 448){
    W = W1; T = W1T; K = 128; M = 256; idx = (b - 320) * 256 + threadIdx.x;
  } else {
    W = W2; T = W2T; K = 256; M = 128; idx = (b - 448) * 256 + threadIdx.x;
  }
  int m = idx / K, k = idx - m * K;
  T[idx] = (__bf16)W[(size_t)k * M + m];
}

// ---------------- parallel 3-phase exclusive scan of deg -> off, cursor ----------------
__global__ __launch_bounds__(256) void k_scanA(const int* __restrict__ deg,
    int* __restrict__ part, int N)
{
  __shared__ int ls[256];
  int b = blockIdx.x, t = threadIdx.x;
  int i = b * 256 + t;
  ls[t] = (i < N) ? deg[i] : 0;
  __syncthreads();
  for (int d = 128; d > 0; d >>= 1){
    if (t < d) ls[t] += ls[t + d];
    __syncthreads();
  }
  if (t == 0) part[b] = ls[0];
}

__global__ __launch_bounds__(256) void k_scanB(int* __restrict__ part, int nb)
{
  __shared__ int ls[256];
  int t = threadIdx.x;
  ls[t] = (t < nb) ? part[t] : 0;
  __syncthreads();
  for (int d = 1; d < 256; d <<= 1){
    int add = (t >= d) ? ls[t - d] : 0;
    __syncthreads();
    ls[t] += add;
    __syncthreads();
  }
  if (t < nb) part[t] = (t == 0) ? 0 : ls[t - 1];   // exclusive block offsets
}

__global__ __launch_bounds__(256) void k_scanC(const int* __restrict__ deg,
    const int* __restrict__ part, int* __restrict__ off, int* __restrict__ cursor, int N)
{
  __shared__ int ls[256];
  int b = blockIdx.x, t = threadIdx.x;
  int i = b * 256 + t;
  int v = (i < N) ? deg[i] : 0;
  ls[t] = v;
  __syncthreads();
  for (int d = 1; d < 256; d <<= 1){
    int add = (t >= d) ? ls[t - d] : 0;
    __syncthreads();
    ls[t] += add;
    __syncthreads();
  }
  if (i < N){
    int excl = ls[t] - v + part[b];
    off[i] = excl;
    cursor[i] = excl;
  }
}

// ---------------- K1: Q,K,V = h @ Wq/Wk/Wv  (bf16 outputs) ----------------
__global__ __launch_bounds__(256) void k_qkv(const float* __restrict__ h,
    const __bf16* __restrict__ WqT, const __bf16* __restrict__ WkT, const __bf16* __restrict__ WvT,
    __bf16* __restrict__ Q, __bf16* __restrict__ K, __bf16* __restrict__ V, int N)
{
  int lane = threadIdx.x & 63;
  int r0 = (blockIdx.x * 4 + (threadIdx.x >> 6)) * 16;
  if (r0 + 16 > N) return;
  bf8 a[4];
  int arow = r0 + (lane & 15);
  int koff = (lane >> 4) << 3;
#pragma unroll
  for (int kt = 0; kt < 4; ++kt)
    a[kt] = cvt8(h + (size_t)arow * DM + kt * 32 + koff);

  const __bf16* Ws[3] = {WqT, WkT, WvT};
  __bf16* Os[3] = {Q, K, V};
  int crow = r0 + ((lane >> 4) << 2);
  int ccol = lane & 15;
#pragma unroll
  for (int o = 0; o < 3; ++o){
#pragma unroll
    for (int nt = 0; nt < 8; ++nt){
      f4 acc = {0.f, 0.f, 0.f, 0.f};
#pragma unroll
      for (int kt = 0; kt < 4; ++kt)
        acc = mfma16(a[kt], bfragT(Ws[o] + (size_t)(nt * 16) * DM + kt * 32, DM, lane), acc);
      __bf16* outp = Os[o] + (size_t)crow * DM + nt * 16 + ccol;
      outp[0] = (__bf16)acc[0]; outp[DM] = (__bf16)acc[1];
      outp[2 * DM] = (__bf16)acc[2]; outp[3 * DM] = (__bf16)acc[3];
    }
  }
}

// ---------------- K2: persistent pipelined Eh GEMM + edge scoring (frozen since R12) ----------------
__global__ __launch_bounds__(256) void k_edge(const float* __restrict__ e,
    const __bf16* __restrict__ WeT,
    const __bf16* __restrict__ Qb, const __bf16* __restrict__ Kb,
    const int* __restrict__ src, const int* __restrict__ dst,
    int* __restrict__ cursor, int* __restrict__ sSrc, float* __restrict__ sS,
    int E, int T, int NW)
{
  __shared__ __bf16 Eh[64][132];
  int tid = threadIdx.x, lane = tid & 63, wave = tid >> 6;
  int l16 = lane & 15;
  int koff = (lane >> 4) << 3;
  int half = lane >> 5, l32 = lane & 31, hh = l32 >> 2;
  int lrow = (lane >> 4) << 2;
  int wrow = wave * 16;
  int t = blockIdx.x * 4 + wave;
  if (t >= T) return;

  // ---- prologue: stage tile t ----
  int ei = min(t * 16 + l16, E - 1);
  int sv = src[ei], dv = dst[ei];
  int slotv = 0;
  if ((lane < 16) && (t * 16 + l16 < E)){
    slotv = atomicAdd(&cursor[dv], 1);
    sSrc[slotv] = sv;
  }
  f4 eu[4], ew[4];
#pragma unroll
  for (int kt = 0; kt < 4; ++kt){
    const float* p = e + (size_t)ei * DM + kt * 32 + koff;
    eu[kt] = *(const f4*)p; ew[kt] = *(const f4*)(p + 4);
  }
  bf4 kr[8], qr[8];
#pragma unroll
  for (int i = 0; i < 8; ++i){
    int js = __shfl(sv, i * 2 + half, 64);
    int jd = __shfl(dv, i * 2 + half, 64);
    kr[i] = *(const bf4*)(Kb + (size_t)js * DM + l32 * 4);
    qr[i] = *(const bf4*)(Qb + (size_t)jd * DM + l32 * 4);
  }

  while (t < T){
    int tn = t + NW;
    bool hn = (tn < T);
    // A fragments
    bf8 a[4];
#pragma unroll
    for (int kt = 0; kt < 4; ++kt){
      bf8 r;
      r[0]=(__bf16)eu[kt][0]; r[1]=(__bf16)eu[kt][1]; r[2]=(__bf16)eu[kt][2]; r[3]=(__bf16)eu[kt][3];
      r[4]=(__bf16)ew[kt][0]; r[5]=(__bf16)ew[kt][1]; r[6]=(__bf16)ew[kt][2]; r[7]=(__bf16)ew[kt][3];
      a[kt] = r;
    }
    // next-tile meta loads (early issue)
    int svn = 0, dvn = 0, slotn = 0;
    if (hn){
      int ein = min(tn * 16 + l16, E - 1);
      svn = src[ein]; dvn = dst[ein];
    }
    // MFMA tile t -> wave-private Eh rows
#pragma unroll
    for (int nt = 0; nt < 8; ++nt){
      f4 acc = {0.f, 0.f, 0.f, 0.f};
#pragma unroll
      for (int kt = 0; kt < 4; ++kt)
        acc = mfma16(a[kt], bfragT(WeT + (size_t)(nt * 16) * DM + kt * 32, DM, lane), acc);
      int col = nt * 16 + l16;
#pragma unroll
      for (int r = 0; r < 4; ++r) Eh[wrow + lrow + r][col] = (__bf16)acc[r];
    }
    // stage next e-rows + next slot (latency hides under consume below)
    if (hn){
      int ern = min(tn * 16 + l16, E - 1);
#pragma unroll
      for (int kt = 0; kt < 4; ++kt){
        const float* p = e + (size_t)ern * DM + kt * 32 + koff;
        eu[kt] = *(const f4*)p; ew[kt] = *(const f4*)(p + 4);
      }
      if ((lane < 16) && (tn * 16 + l16 < E)){
        slotn = atomicAdd(&cursor[dvn], 1);
        sSrc[slotn] = svn;
      }
    }
    // consume part 1: dot products + reduce (frees kr/qr)
    float ds[8];
#pragma unroll
    for (int q = 0; q < 8; ++q){
      bf4 evv = *(const bf4*)&Eh[wrow + q * 2 + half][l32 * 4];
      bf4 kv = kr[q], qv = qr[q];
      float d = (float)kv[0]*(float)qv[0]*(float)evv[0]
              + (float)kv[1]*(float)qv[1]*(float)evv[1]
              + (float)kv[2]*(float)qv[2]*(float)evv[2]
              + (float)kv[3]*(float)qv[3]*(float)evv[3];
      d += __shfl_xor(d, 1);
      d += __shfl_xor(d, 2);
      ds[q] = d;
    }
    // issue next-tile gathers now that kr/qr are dead (cover expf + next MFMA)
    if (hn){
#pragma unroll
      for (int i = 0; i < 8; ++i){
        int js = __shfl(svn, i * 2 + half, 64);
        int jd = __shfl(dvn, i * 2 + half, 64);
        kr[i] = *(const bf4*)(Kb + (size_t)js * DM + l32 * 4);
        qr[i] = *(const bf4*)(Qb + (size_t)jd * DM + l32 * 4);
      }
    }
    // consume part 2: broadcast slots wave-uniformly (width 64!), then clamp/exp/store
    int jslot[8];
#pragma unroll
    for (int q = 0; q < 8; ++q) jslot[q] = __shfl(slotv, q * 2 + half, 64);
    if ((l32 & 3) == 0){
#pragma unroll
      for (int q = 0; q < 8; ++q){
        if ((t * 16 + q * 2 + half) < E){
          float dd = fminf(5.f, fmaxf(-5.f, ds[q] * 0.25f));
          sS[(size_t)jslot[q] * NH + hh] = __expf(dd);
        }
      }
    }
    sv = svn; dv = dvn; slotv = slotn;
    t = tn;
  }
}

// ---------------- K3: fused per-node gather + (wV/z)@Wo + residual + BN1 stats ----------------
// phase A unrolled 4x: four nodes' gather chains in flight per wave
__global__ __launch_bounds__(256) void k_gat_attnout(const int* __restrict__ off,
    const int* __restrict__ cend, const int* __restrict__ sSrc, const float* __restrict__ sS,
    const __bf16* __restrict__ Vb,
    const float* __restrict__ h, const __bf16* __restrict__ WoT, const float* __restrict__ bo,
    __bf16* __restrict__ h2, float* __restrict__ s1, float* __restrict__ s2, int N)
{
  __shared__ __bf16 hat[64][132];   // gathered normalized h_attn tile (bf16)
  __shared__ float ls[256];
  int tid = threadIdx.x, lane = tid & 63, wave = tid >> 6;
  int half = lane >> 5, l32 = lane & 31, hh = l32 >> 2;
  int node0 = blockIdx.x * 64;
  ls[tid] = 0.f;

  // ---- phase A: gather 16 nodes per wave (2 at a time across half-waves; 4 iterations interleaved) ----
#pragma unroll 4
  for (int it = 0; it < 8; ++it){
    int local = wave * 16 + it * 2 + half;
    int node = node0 + local;
    int nodec = min(node, N - 1);
    int start = off[nodec], end = cend[nodec];
    float a0 = 0.f, a1 = 0.f, a2 = 0.f, a3 = 0.f, z = 0.f;
    for (int base = start; base < end; base += 8){
      int idx[8], sj[8]; float s[8];
#pragma unroll
      for (int q = 0; q < 8; ++q) idx[q] = min(base + q, end - 1);
#pragma unroll
      for (int q = 0; q < 8; ++q) sj[q] = sSrc[idx[q]];
#pragma unroll
      for (int q = 0; q < 8; ++q) s[q] = (base + q < end) ? sS[(size_t)idx[q] * NH + hh] : 0.f;
#pragma unroll
      for (int q = 0; q < 8; ++q){
        bf4 v = *(const bf4*)(Vb + (size_t)sj[q] * DM + l32 * 4);
        a0 += s[q] * (float)v[0]; a1 += s[q] * (float)v[1];
        a2 += s[q] * (float)v[2]; a3 += s[q] * (float)v[3];
        z += s[q];
      }
    }
    float invz = 1.f / (z + 1e-6f);
    bf4 o;
    o[0] = (__bf16)(a0 * invz); o[1] = (__bf16)(a1 * invz);
    o[2] = (__bf16)(a2 * invz); o[3] = (__bf16)(a3 * invz);
    *(bf4*)&hat[local][l32 * 4] = o;
  }
  __syncthreads();

  // ---- phase B: h2 = h + hat @ Wo + bo, with BN1 stats ----
  int r0 = node0 + wave * 16;
  bool active = (r0 + 16 <= N);
  int r0c = active ? r0 : 0;
  int kof = (lane >> 4) << 3;
  bf8 a[4];
#pragma unroll
  for (int kt = 0; kt < 4; ++kt)
    a[kt] = *(const bf8*)&hat[wave * 16 + (lane & 15)][kt * 32 + kof];
  int crow = r0c + ((lane >> 4) << 2);
  int ccol = lane & 15;
#pragma unroll
  for (int nt = 0; nt < 8; ++nt){
    f4 acc = {0.f, 0.f, 0.f, 0.f};
#pragma unroll
    for (int kt = 0; kt < 4; ++kt)
      acc = mfma16(a[kt], bfragT(WoT + (size_t)(nt * 16) * DM + kt * 32, DM, lane), acc);
    int col = nt * 16 + ccol;
    float bb = bo[col];
    if (active){
      float p1 = 0.f, p2 = 0.f;
#pragma unroll
      for (int r = 0; r < 4; ++r){
        size_t idx = (size_t)(crow + r) * DM + col;
        float v = h[idx] + acc[r] + bb;
        h2[idx] = (__bf16)v;
        p1 += v; p2 += v * v;
      }
      atomicAdd(&ls[col], p1);
      atomicAdd(&ls[128 + col], p2);
    }
  }
  __syncthreads();
  if (tid < 128){
    atomicAdd(&s1[tid], ls[tid]);
    atomicAdd(&s2[tid], ls[128 + tid]);
  }
}

// ---------------- K6: FFN fused, BN1 coefs per-block, bf16 output + BN2 stats ----------------
__global__ __launch_bounds__(256) void k_ffn(const __bf16* __restrict__ h2,
    const float* __restrict__ s1a, const float* __restrict__ s2a,
    const float* __restrict__ g1, const float* __restrict__ be1,
    const __bf16* __restrict__ W1T, const float* __restrict__ b1,
    const __bf16* __restrict__ W2T, const float* __restrict__ b2,
    __bf16* __restrict__ y, float* __restrict__ s1, float* __restrict__ s2, int N)
{
  __shared__ __bf16 hid[4][16][264];   // padded: breaks 16-way bank conflict on GEMM2 reads
  __shared__ float ls[256];
  __shared__ float cls[128], clb[128];
  int tid = threadIdx.x;
  ls[tid] = 0.f;
  if (tid < 128){
    float mean = s1a[tid] / (float)N;
    float var  = s2a[tid] / (float)N - mean * mean;
    float rs   = rsqrtf(var + 1e-5f);
    float sc   = g1[tid] * rs;
    cls[tid] = sc;
    clb[tid] = be1[tid] - mean * sc;
  }
  __syncthreads();
  int lane = tid & 63, wave = tid >> 6;
  int r0 = (blockIdx.x * 4 + wave) * 16;
  bool active = (r0 + 16 <= N);
  int r0c = active ? r0 : 0;

  int arow = r0c + (lane & 15);
  int kof = (lane >> 4) << 3;
  bf8 a[4];
#pragma unroll
  for (int kt = 0; kt < 4; ++kt){
    int kb = kt * 32 + kof;
    bf8 hv = *(const bf8*)(h2 + (size_t)arow * DM + kb);
    bf8 r;
#pragma unroll
    for (int j = 0; j < 8; ++j)
      r[j] = (__bf16)((float)hv[j] * cls[kb + j] + clb[kb + j]);
    a[kt] = r;
  }
  int lr = (lane >> 4) << 2;
  int ccol = lane & 15;
#pragma unroll
  for (int nt = 0; nt < 16; ++nt){
    f4 acc = {0.f, 0.f, 0.f, 0.f};
#pragma unroll
    for (int kt = 0; kt < 4; ++kt)
      acc = mfma16(a[kt], bfragT(W1T + (size_t)(nt * 16) * DM + kt * 32, DM, lane), acc);
    int col = nt * 16 + ccol;
    float bb = b1[col];
#pragma unroll
    for (int r = 0; r < 4; ++r)
      hid[wave][lr + r][col] = (__bf16)fmaxf(acc[r] + bb, 0.f);
  }
  __syncthreads();
  f4 acc2[8];
#pragma unroll
  for (int nt = 0; nt < 8; ++nt){ acc2[nt][0]=0.f; acc2[nt][1]=0.f; acc2[nt][2]=0.f; acc2[nt][3]=0.f; }
#pragma unroll
  for (int kt = 0; kt < 8; ++kt){
    bf8 a2 = *(const bf8*)&hid[wave][lane & 15][kt * 32 + kof];
#pragma unroll
    for (int nt = 0; nt < 8; ++nt)
      acc2[nt] = mfma16(a2, bfragT(W2T + (size_t)(nt * 16) * 256 + kt * 32, 256, lane), acc2[nt]);
  }
  int crow = r0c + lr;
#pragma unroll
  for (int nt = 0; nt < 8; ++nt){
    int col = nt * 16 + ccol;
    float bb = b2[col], sc = cls[col], sb = clb[col];
    if (active){
      float p1 = 0.f, p2 = 0.f;
#pragma unroll
      for (int r = 0; r < 4; ++r){
        size_t idx = (size_t)(crow + r) * DM + col;
        float xres = (float)h2[idx] * sc + sb;
        float v = acc2[nt][r] + bb + xres;
        __bf16 vb = (__bf16)v;
        y[idx] = vb;
        float vr = (float)vb;        // stats on rounded value => BN exact over y
        p1 += vr; p2 += vr * vr;
      }
      atomicAdd(&ls[col], p1);
      atomicAdd(&ls[128 + col], p2);
    }
  }
  __syncthreads();
  if (tid < 128){
    atomicAdd(&s1[tid], ls[tid]);
    atomicAdd(&s2[tid], ls[128 + tid]);
  }
}

// ---------------- BN2 apply: bf16 in -> f32 out, per-block coef recompute ----------------
__global__ __launch_bounds__(256) void k_bnapply(const __bf16* __restrict__ y,
    float* __restrict__ out,
    const float* __restrict__ s1, const float* __restrict__ s2,
    const float* __restrict__ gam, const float* __restrict__ bet,
    int N, long long total4)
{
  __shared__ float cs[128], cb[128];
  int tid = threadIdx.x;
  if (tid < 128){
    float mean = s1[tid] / (float)N;
    float var  = s2[tid] / (float)N - mean * mean;
    float rs   = rsqrtf(var + 1e-5f);
    float sc   = gam[tid] * rs;
    cs[tid] = sc;
    cb[tid] = bet[tid] - mean * sc;
  }
  __syncthreads();
  long long i = (long long)blockIdx.x * blockDim.x + tid;
  if (i >= total4) return;
  bf4 v = *((const bf4*)y + i);
  int c = (int)((i * 4) & (DM - 1));
  f4 o;
  o[0] = (float)v[0] * cs[c]     + cb[c];
  o[1] = (float)v[1] * cs[c + 1] + cb[c + 1];
  o[2] = (float)v[2] * cs[c + 2] + cb[c + 2];
  o[3] = (float)v[3] * cs[c + 3] + cb[c + 3];
  *((f4*)out + i) = o;
}

// ---------------- host ----------------
extern "C" void kernel_launch(void* const* d_in, const int* in_sizes, int n_in,
                              void* d_out, int out_size, void* d_ws, size_t ws_size,
                              hipStream_t stream)
{
  const float* h    = (const float*)d_in[0];
  const float* e    = (const float*)d_in[2];
  const float* Wq   = (const float*)d_in[3];
  const float* Wk   = (const float*)d_in[4];
  const float* We   = (const float*)d_in[5];
  const float* Wv   = (const float*)d_in[6];
  const float* Wo   = (const float*)d_in[7];
  const float* bo   = (const float*)d_in[8];
  const float* bn1g = (const float*)d_in[9];
  const float* bn1b = (const float*)d_in[10];
  const float* bn2g = (const float*)d_in[11];
  const float* bn2b = (const float*)d_in[12];
  const float* W1   = (const float*)d_in[13];
  const float* b1   = (const float*)d_in[14];
  const float* W2   = (const float*)d_in[15];
  const float* b2   = (const float*)d_in[16];
  const int*   src  = (const int*)d_in[17];
  const int*   dst  = (const int*)d_in[18];

  int N = in_sizes[0] / DM;
  int E = in_sizes[2] / DM;
  float* out = (float*)d_out;

  char* ws = (char*)d_ws;
  size_t off_b = 0;
  auto alloc = [&](size_t bytes) -> char* {
    char* r = ws + off_b;
    off_b += (bytes + 255) & ~(size_t)255;
    return r;
  };
  __bf16* Qb    = (__bf16*)alloc((size_t)N * DM * 2);
  __bf16* Kb    = (__bf16*)alloc((size_t)N * DM * 2);
  __bf16* Vb    = (__bf16*)alloc((size_t)N * DM * 2);
  __bf16* h2    = (__bf16*)alloc((size_t)N * DM * 2);
  __bf16* y     = (__bf16*)alloc((size_t)N * DM * 2);
  int*   deg    = (int*)alloc((size_t)N * 4);
  int*   offs   = (int*)alloc((size_t)N * 4);
  int*   cursor = (int*)alloc((size_t)N * 4);
  int*   part   = (int*)alloc(256 * 4);
  int*   sSrc   = (int*)alloc((size_t)E * 4);
  float* sS     = (float*)alloc((size_t)E * NH * 4);
  float* stats = (float*)alloc(512 * 4);   // s1a s2a s1b s2b
  float* s1a = stats, *s2a = stats + 128, *s1b = stats + 256, *s2b = stats + 384;
  __bf16* WqT = (__bf16*)alloc(16384 * 2);
  __bf16* WkT = (__bf16*)alloc(16384 * 2);
  __bf16* WvT = (__bf16*)alloc(16384 * 2);
  __bf16* WeT = (__bf16*)alloc(16384 * 2);
  __bf16* WoT = (__bf16*)alloc(16384 * 2);
  __bf16* W1T = (__bf16*)alloc(32768 * 2);
  __bf16* W2T = (__bf16*)alloc(32768 * 2);

  hipMemsetAsync(deg, 0, (size_t)N * 4, stream);
  hipMemsetAsync(stats, 0, 512 * 4, stream);

  int histblocks = (E + 255) / 256;
  k_prep_hist<<<576 + histblocks, 256, 0, stream>>>(Wq, Wk, Wv, We, Wo, W1, W2,
      WqT, WkT, WvT, WeT, WoT, W1T, W2T, dst, deg, E);
  int scb = (N + 255) / 256;    // 196 for N=50000 (fits k_scanB's 256-thread scan)
  k_scanA<<<scb, 256, 0, stream>>>(deg, part, N);
  k_scanB<<<1, 256, 0, stream>>>(part, scb);
  k_scanC<<<scb, 256, 0, stream>>>(deg, part, offs, cursor, N);

  int rowblocks = (N / 16 + 3) / 4;
  k_qkv<<<rowblocks, 256, 0, stream>>>(h, WqT, WkT, WvT, Qb, Kb, Vb, N);
  int T = (E + 15) / 16;
  int eblocks = 2048;
  int NW = eblocks * 4;
  k_edge<<<eblocks, 256, 0, stream>>>(e, WeT, Qb, Kb, src, dst, cursor, sSrc, sS, E, T, NW);
  k_gat_attnout<<<(N + 63) / 64, 256, 0, stream>>>(offs, cursor, sSrc, sS, Vb,
      h, WoT, bo, h2, s1a, s2a, N);
  k_ffn<<<rowblocks, 256, 0, stream>>>(h2, s1a, s2a, bn1g, bn1b, W1T, b1, W2T, b2,
                                       y, s1b, s2b, N);
  long long total4 = (long long)N * DM / 4;
  k_bnapply<<<(int)((total4 + 255) / 256), 256, 0, stream>>>(y, out, s1b, s2b, bn2g, bn2b, N, total4);
}